// Round 17
// baseline (386.951 us; speedup 1.0000x reference)
//
#include <hip/hip_runtime.h>
#include <math.h>

#define TT 2048   // tokens
#define NP 2048   // num params (N)
#define BB 8      // batch
#define DD 512    // d_model = kdim = vdim

#define LOG_A (-7.6246189861593985f)  // -log(2048)
#define CC 30.0f                       // E = exp(CC - dist) shift
#define E30 1.0686475e13f              // exp(30)
#define K0U 5.2180055e9f               // exp(30)/2048

typedef __attribute__((ext_vector_type(8))) _Float16 f16x8;
typedef __attribute__((ext_vector_type(4))) _Float16 f16x4;
typedef __attribute__((ext_vector_type(4))) float f32x4;

#define MFMA_F16(a, b, c)  __builtin_amdgcn_mfma_f32_16x16x32_f16((a), (b), (c), 0, 0, 0)

// ---------------------------------------------------------------------------
// helpers
// ---------------------------------------------------------------------------
__device__ __forceinline__ float f16u2f(unsigned short u) {
    union { unsigned short s; _Float16 h; } v; v.s = u;
    return (float)v.h;
}

// async global->LDS, 16B per lane (wave-uniform LDS base + lane*16, per-lane src)
__device__ __forceinline__ void gload16(const void* g, void* l) {
    __builtin_amdgcn_global_load_lds(
        (const __attribute__((address_space(1))) void*)g,
        (__attribute__((address_space(3))) void*)l, 16, 0, 0);
}

// ---------------------------------------------------------------------------
// LDS tile layout, "k-group-major": tile[s][r][8 elems], s = k-subgroup
// (0..3 => BK=32), r = row. A tile r=0..127 (byte off s*2048 + r*16);
// cost's B tile r=0..255 (byte off s*4096 + r*16).
// A-frag (16x16x32): lane holds A[m=lane%16][k=(lane/16)*8+j]
// B-frag:            lane holds B[k=(lane/16)*8+j][n=lane%16]  (B stored [N][K])
// C/D:               col=lane&15, row=(lane>>4)*4+reg   [m89-verified]
// ---------------------------------------------------------------------------
__device__ __forceinline__ void frag_step_f16(
    const _Float16* sA, const _Float16* sB,
    int lane, int wm, int wn, f32x4 acc[4][4])
{
    const int sb = (lane >> 4) << 11;
    const int rl = (lane & 15) << 4;
    f16x8 a[4], b[4];
    #pragma unroll
    for (int i = 0; i < 4; ++i) {
        a[i] = *(const f16x8*)((const char*)sA + sb + ((wm + i * 16) << 4) + rl);
        b[i] = *(const f16x8*)((const char*)sB + sb + ((wn + i * 16) << 4) + rl);
    }
    #pragma unroll
    for (int i = 0; i < 4; ++i)
        #pragma unroll
        for (int j = 0; j < 4; ++j)
            acc[i][j] = MFMA_F16(a[i], b[j], acc[i][j]);
}

// cost variant: per-wave 64x128 output; A tile [4][128][8], B tile [4][256][8].
__device__ __forceinline__ void frag_step_f16_w(
    const _Float16* sA, const _Float16* sB,
    int lane, int wm, int wn, f32x4 acc[4][8])
{
    const int sbA = (lane >> 4) << 11;
    const int sbB = (lane >> 4) << 12;
    const int rl = (lane & 15) << 4;
    f16x8 a[4], b[8];
    #pragma unroll
    for (int i = 0; i < 4; ++i)
        a[i] = *(const f16x8*)((const char*)sA + sbA + ((wm + i * 16) << 4) + rl);
    #pragma unroll
    for (int j = 0; j < 8; ++j)
        b[j] = *(const f16x8*)((const char*)sB + sbB + ((wn + j * 16) << 4) + rl);
    #pragma unroll
    for (int i = 0; i < 4; ++i)
        #pragma unroll
        for (int j = 0; j < 8; ++j)
            acc[i][j] = MFMA_F16(a[i], b[j], acc[i][j]);
}

__device__ __forceinline__ void zero_acc(f32x4 acc[4][4]) {
    #pragma unroll
    for (int i = 0; i < 4; ++i)
        #pragma unroll
        for (int j = 0; j < 4; ++j)
            acc[i][j] = (f32x4){0.f, 0.f, 0.f, 0.f};
}

__device__ __forceinline__ void store_plain(
    float* C, int N, int row0, int col0, int lane, int wm, int wn, f32x4 acc[4][4])
{
    #pragma unroll
    for (int i = 0; i < 4; ++i)
        #pragma unroll
        for (int j = 0; j < 4; ++j) {
            int colg = col0 + wn + j * 16 + (lane & 15);
            int rowb = row0 + wm + i * 16 + ((lane >> 4) << 2);
            #pragma unroll
            for (int r = 0; r < 4; ++r)
                C[(size_t)(rowb + r) * N + colg] = acc[i][j][r];
        }
}

// ---------------------------------------------------------------------------
// Transpose 3 weights to fp16 in ONE launch. Grid (8,8,3).
// ---------------------------------------------------------------------------
__global__ __launch_bounds__(256) void transpose3_f16(
    const float* __restrict__ X0, const float* __restrict__ X1,
    const float* __restrict__ X2, _Float16* __restrict__ o0,
    _Float16* __restrict__ o1, _Float16* __restrict__ o2)
{
    const int z = blockIdx.z;
    const float* Xb = (z == 0) ? X0 : (z == 1) ? X1 : X2;
    _Float16* ob = (z == 0) ? o0 : (z == 1) ? o1 : o2;
    __shared__ float t[64][65];
    const int bx = blockIdx.x * 64;
    const int by = blockIdx.y * 64;
    const int tx = threadIdx.x & 63, ty = threadIdx.x >> 6;
    #pragma unroll
    for (int r = ty; r < 64; r += 4)
        t[r][tx] = Xb[(size_t)(by + r) * 512 + bx + tx];
    __syncthreads();
    #pragma unroll
    for (int r = ty; r < 64; r += 4)
        ob[(size_t)(bx + r) * 512 + by + tx] = (_Float16)t[tx][r];
}

// ---------------------------------------------------------------------------
// Merged q+k projection GEMM (NT, fp16), 2-phase dbuf prefetch. Grid (4,144).
// ---------------------------------------------------------------------------
__global__ __launch_bounds__(256) void gemm_projqk_f16(
    const float* __restrict__ Aq, const float* __restrict__ Ak,
    const _Float16* __restrict__ Btq, const _Float16* __restrict__ Btk,
    _Float16* __restrict__ C)
{
    const int by = blockIdx.y;
    const bool isq = (by < 16);
    const float* A = isq ? Aq : Ak;
    const _Float16* Bt = isq ? Btq : Btk;
    const int arow0 = isq ? by * 128 : (by - 16) * 128;
    const int crow0 = by * 128;
    const int col0 = blockIdx.x * 128;

    __shared__ __attribute__((aligned(16))) _Float16 sA[2][4096], sB[2][4096];
    const int tid = threadIdx.x;
    const int lane = tid & 63;
    const int wm = ((tid >> 7) & 1) * 64;
    const int wn = ((tid >> 6) & 1) * 64;
    f32x4 acc[4][4];
    zero_acc(acc);

    auto STAGE = [&](int buf, int k0) {
        #pragma unroll
        for (int q = 0; q < 2; ++q) {
            int o = (tid + (q << 8)) << 4;
            int s = o >> 11;
            int r = (o & 2047) >> 4;
            gload16(Bt + (size_t)(col0 + r) * DD + k0 + s * 8, (char*)&sB[buf][0] + o);
            const float* src = A + (size_t)(arow0 + r) * DD + k0 + s * 8;
            float4 f0 = *(const float4*)src;
            float4 f1 = *(const float4*)(src + 4);
            _Float16 hs[8] = {(_Float16)f0.x, (_Float16)f0.y,
                              (_Float16)f0.z, (_Float16)f0.w,
                              (_Float16)f1.x, (_Float16)f1.y,
                              (_Float16)f1.z, (_Float16)f1.w};
            *(f16x8*)((char*)&sA[buf][0] + o) = *(f16x8*)hs;
        }
    };

    STAGE(0, 0);
    __syncthreads();
    int cur = 0;
    for (int k0 = 0; k0 < DD; k0 += 32) {
        if (k0 + 32 < DD) STAGE(cur ^ 1, k0 + 32);
        frag_step_f16(&sA[cur][0], &sB[cur][0], lane, wm, wn, acc);
        __syncthreads();
        cur ^= 1;
    }
    #pragma unroll
    for (int i = 0; i < 4; ++i)
        #pragma unroll
        for (int j = 0; j < 4; ++j) {
            int colg = col0 + wn + j * 16 + (lane & 15);
            int rowb = crow0 + wm + i * 16 + ((lane >> 4) << 2);
            #pragma unroll
            for (int r = 0; r < 4; ++r)
                C[(size_t)(rowb + r) * DD + colg] = (_Float16)acc[i][j][r];
        }
}

// ---------------------------------------------------------------------------
// v projection GEMM (NT, fp16), 2-phase dbuf prefetch: writes vpT directly.
// ---------------------------------------------------------------------------
__global__ __launch_bounds__(256) void gemm_projv_f16(
    const float* __restrict__ A, const _Float16* __restrict__ Bt,
    _Float16* __restrict__ C)
{
    __shared__ __attribute__((aligned(16))) _Float16 sA[2][4096], sB[2][4096];
    const int tid = threadIdx.x;
    const int lane = tid & 63;
    const int row0 = blockIdx.y * 128;
    const int col0 = blockIdx.x * 128;
    const int wm = ((tid >> 7) & 1) * 64;
    const int wn = ((tid >> 6) & 1) * 64;
    f32x4 acc[4][4];
    zero_acc(acc);

    auto STAGE = [&](int buf, int k0) {
        #pragma unroll
        for (int q = 0; q < 2; ++q) {
            int o = (tid + (q << 8)) << 4;
            int s = o >> 11;
            int r = (o & 2047) >> 4;
            gload16(Bt + (size_t)(col0 + r) * DD + k0 + s * 8, (char*)&sB[buf][0] + o);
            const float* src = A + (size_t)(row0 + r) * DD + k0 + s * 8;
            float4 f0 = *(const float4*)src;
            float4 f1 = *(const float4*)(src + 4);
            _Float16 hs[8] = {(_Float16)f0.x, (_Float16)f0.y,
                              (_Float16)f0.z, (_Float16)f0.w,
                              (_Float16)f1.x, (_Float16)f1.y,
                              (_Float16)f1.z, (_Float16)f1.w};
            *(f16x8*)((char*)&sA[buf][0] + o) = *(f16x8*)hs;
        }
    };

    STAGE(0, 0);
    __syncthreads();
    int cur = 0;
    for (int k0 = 0; k0 < DD; k0 += 32) {
        if (k0 + 32 < DD) STAGE(cur ^ 1, k0 + 32);
        frag_step_f16(&sA[cur][0], &sB[cur][0], lane, wm, wn, acc);
        __syncthreads();
        cur ^= 1;
    }
    #pragma unroll
    for (int i = 0; i < 4; ++i)
        #pragma unroll
        for (int j = 0; j < 4; ++j) {
            int colg = col0 + wn + j * 16 + (lane & 15);
            int rowb = row0 + wm + i * 16 + ((lane >> 4) << 2);
            int b = rowb >> 11;
            int n0 = rowb & (NP - 1);
            _Float16 h4[4];
            #pragma unroll
            for (int r = 0; r < 4; ++r) h4[r] = (_Float16)acc[i][j][r];
            *(f16x4*)(C + (size_t)b * DD * NP + (size_t)colg * NP + n0) =
                *(f16x4*)h4;
        }
}

// ---------------------------------------------------------------------------
// Row squared-norm from fp16 (merged qp+kp). One wave per row.
// ---------------------------------------------------------------------------
__global__ __launch_bounds__(256) void rownorm_f16(
    const _Float16* __restrict__ X, float* __restrict__ o, int rows)
{
    int w = blockIdx.x * 4 + (threadIdx.x >> 6);
    int lane = threadIdx.x & 63;
    if (w >= rows) return;
    f16x8 v = *(const f16x8*)(X + (size_t)w * DD + lane * 8);
    float s = 0.f;
    #pragma unroll
    for (int j = 0; j < 8; ++j) {
        float x = (float)v[j];
        s = fmaf(x, x, s);
    }
    #pragma unroll
    for (int off = 32; off; off >>= 1) s += __shfl_down(s, off, 64);
    if (lane == 0) o[w] = s;
}

// ---------------------------------------------------------------------------
// Cost GEMM, tile 128x256 (BM=128, BN=256), 3-buffer counted-vmcnt pipeline
// + FUSED first-u colsum. 4 waves, each 64x128 output (acc[4][8]).
// STAGE = 6 gload16/thread (A 8KB + B 16KB per K-step); steady wait vmcnt(6).
// Grid 1024 blocks, XCD-chunked swizzle (batch per XCD).
// ---------------------------------------------------------------------------
__global__ __launch_bounds__(256) void gemm_cost_f16(
    const _Float16* __restrict__ A, const _Float16* __restrict__ B,
    const float* __restrict__ q2, const float* __restrict__ k2,
    _Float16* __restrict__ E, float* __restrict__ ps16)
{
    const int bid = blockIdx.x;
    const int sid = ((bid & 7) << 7) | (bid >> 3);   // 1024 blocks, 128/XCD
    const int b  = sid >> 7;
    const int by = (sid >> 3) & 15;   // M tile (128 rows)
    const int bx = sid & 7;           // N tile (256 cols)

    const _Float16* Bb = B + (size_t)b * NP * DD;
    const float* k2b = k2 + (size_t)b * NP;
    _Float16* Cb = E + (size_t)b * TT * NP;

    __shared__ __attribute__((aligned(16))) _Float16 sA[3][4096], sB[3][8192];
    __shared__ float colbuf[2][256];
    const int tid = threadIdx.x;
    const int lane = tid & 63;
    const int row0 = by * 128;   // t
    const int col0 = bx * 256;   // n
    const int wm = ((tid >> 7) & 1) * 64;
    const int wn = ((tid >> 6) & 1) * 128;
    f32x4 acc[4][8];
    #pragma unroll
    for (int i = 0; i < 4; ++i)
        #pragma unroll
        for (int j = 0; j < 8; ++j)
            acc[i][j] = (f32x4){0.f, 0.f, 0.f, 0.f};

    auto STAGE = [&](int buf, int k0) {
        #pragma unroll
        for (int q = 0; q < 2; ++q) {
            int o = (tid + (q << 8)) << 4;
            int s = o >> 11;
            int r = (o & 2047) >> 4;
            gload16(A + (size_t)(row0 + r) * DD + k0 + s * 8, (char*)&sA[buf][0] + o);
        }
        #pragma unroll
        for (int q = 0; q < 4; ++q) {
            int o = (tid + (q << 8)) << 4;
            int s = o >> 12;
            int r = (o & 4095) >> 4;
            gload16(Bb + (size_t)(col0 + r) * DD + k0 + s * 8, (char*)&sB[buf][0] + o);
        }
    };

    STAGE(0, 0);
    STAGE(1, 32);
    #pragma unroll
    for (int s = 0; s < 14; ++s) {
        asm volatile("s_waitcnt vmcnt(6)" ::: "memory");
        __builtin_amdgcn_s_barrier();
        __builtin_amdgcn_sched_barrier(0);
        STAGE((s + 2) % 3, (s + 2) * 32);
        frag_step_f16_w(&sA[s % 3][0], &sB[s % 3][0], lane, wm, wn, acc);
    }
    asm volatile("s_waitcnt vmcnt(6)" ::: "memory");
    __builtin_amdgcn_s_barrier();
    __builtin_amdgcn_sched_barrier(0);
    frag_step_f16_w(&sA[2][0], &sB[2][0], lane, wm, wn, acc);
    asm volatile("s_waitcnt vmcnt(0)" ::: "memory");
    __builtin_amdgcn_s_barrier();
    __builtin_amdgcn_sched_barrier(0);
    frag_step_f16_w(&sA[0][0], &sB[0][0], lane, wm, wn, acc);

    // epilogue: E stores (scattered, R12-proven) + per-lane colsum
    float csum[8] = {0.f, 0.f, 0.f, 0.f, 0.f, 0.f, 0.f, 0.f};
    #pragma unroll
    for (int i = 0; i < 4; ++i)
        #pragma unroll
        for (int j = 0; j < 8; ++j) {
            int colg = col0 + wn + j * 16 + (lane & 15);
            float k2v = k2b[colg];
            int rowb = row0 + wm + i * 16 + ((lane >> 4) << 2);
            #pragma unroll
            for (int r = 0; r < 4; ++r) {
                float sq = fmaxf(q2[rowb + r] + k2v - 2.f * acc[i][j][r], 0.f);
                float dist = sq * __frsqrt_rn(fmaxf(sq, 1e-20f));
                float e = fminf(__expf(CC - dist), 60000.f);
                csum[j] += e;
                Cb[(size_t)(rowb + r) * NP + colg] = (_Float16)e;
            }
        }
    // reduce the 4 lane-groups sharing each column
    #pragma unroll
    for (int j = 0; j < 8; ++j) {
        float s = csum[j];
        s += __shfl_down(s, 32, 64);
        s += __shfl_down(s, 16, 64);
        if (lane < 16)
            colbuf[wm >> 6][wn + j * 16 + lane] = s;
    }
    __syncthreads();
    ps16[((size_t)b * 16 + by) * NP + col0 + tid] =
        colbuf[0][tid] + colbuf[1][tid];
}

// ---------------------------------------------------------------------------
// Fused Sinkhorn pass: block = 32 rows x 2048 cols. Per 8-row group:
// S_t = sum E*U -> Y = E30/S (in-kernel), then colsum E*Y -> ps[b][chunk][n].
// Grid (TT/32, BB) = 512 blocks, 64 chunks.
// ---------------------------------------------------------------------------
__global__ __launch_bounds__(256) void sink_fused(
    const _Float16* __restrict__ E, const float* __restrict__ U,
    float* __restrict__ ps)
{
    const int b = blockIdx.y;
    const int t0 = blockIdx.x * 32;
    const int tid = threadIdx.x;
    const int n0 = tid * 8;
    const _Float16* Eb = E + ((size_t)b * TT + t0) * NP;

    float u8[8];
    {
        float4 a = *(const float4*)(U + (size_t)b * NP + n0);
        float4 c = *(const float4*)(U + (size_t)b * NP + n0 + 4);
        u8[0] = a.x; u8[1] = a.y; u8[2] = a.z; u8[3] = a.w;
        u8[4] = c.x; u8[5] = c.y; u8[6] = c.z; u8[7] = c.w;
    }

    float cs[8] = {0.f, 0.f, 0.f, 0.f, 0.f, 0.f, 0.f, 0.f};
    __shared__ float red[8][256];
    __shared__ float yy[8];

    #pragma unroll
    for (int g = 0; g < 4; ++g) {
        uint4 ev[8];
        #pragma unroll
        for (int r = 0; r < 8; ++r)
            ev[r] = *(const uint4*)(Eb + (size_t)(g * 8 + r) * NP + n0);

        #pragma unroll
        for (int r = 0; r < 8; ++r) {
            float d = 0.f;
            d = fmaf(f16u2f((unsigned short)(ev[r].x & 0xFFFFu)), u8[0], d);
            d = fmaf(f16u2f((unsigned short)(ev[r].x >> 16)),     u8[1], d);
            d = fmaf(f16u2f((unsigned short)(ev[r].y & 0xFFFFu)), u8[2], d);
            d = fmaf(f16u2f((unsigned short)(ev[r].y >> 16)),     u8[3], d);
            d = fmaf(f16u2f((unsigned short)(ev[r].z & 0xFFFFu)), u8[4], d);
            d = fmaf(f16u2f((unsigned short)(ev[r].z >> 16)),     u8[5], d);
            d = fmaf(f16u2f((unsigned short)(ev[r].w & 0xFFFFu)), u8[6], d);
            d = fmaf(f16u2f((unsigned short)(ev[r].w >> 16)),     u8[7], d);
            red[r][tid] = d;
        }
        __syncthreads();
        {
            int w = tid >> 6, lane = tid & 63;
            #pragma unroll
            for (int rr = 0; rr < 2; ++rr) {
                int r = w * 2 + rr;
                float s = red[r][lane] + red[r][lane + 64] +
                          red[r][lane + 128] + red[r][lane + 192];
                #pragma unroll
                for (int off = 32; off; off >>= 1)
                    s += __shfl_down(s, off, 64);
                if (lane == 0) yy[r] = E30 / s;
            }
        }
        __syncthreads();
        #pragma unroll
        for (int r = 0; r < 8; ++r) {
            float yv = yy[r];
            cs[0] = fmaf(f16u2f((unsigned short)(ev[r].x & 0xFFFFu)), yv, cs[0]);
            cs[1] = fmaf(f16u2f((unsigned short)(ev[r].x >> 16)),     yv, cs[1]);
            cs[2] = fmaf(f16u2f((unsigned short)(ev[r].y & 0xFFFFu)), yv, cs[2]);
            cs[3] = fmaf(f16u2f((unsigned short)(ev[r].y >> 16)),     yv, cs[3]);
            cs[4] = fmaf(f16u2f((unsigned short)(ev[r].z & 0xFFFFu)), yv, cs[4]);
            cs[5] = fmaf(f16u2f((unsigned short)(ev[r].z >> 16)),     yv, cs[5]);
            cs[6] = fmaf(f16u2f((unsigned short)(ev[r].w & 0xFFFFu)), yv, cs[6]);
            cs[7] = fmaf(f16u2f((unsigned short)(ev[r].w >> 16)),     yv, cs[7]);
        }
        __syncthreads();
    }

    size_t o = ((size_t)b * 64 + blockIdx.x) * NP + n0;
    *(float4*)(ps + o)     = make_float4(cs[0], cs[1], cs[2], cs[3]);
    *(float4*)(ps + o + 4) = make_float4(cs[4], cs[5], cs[6], cs[7]);
}

// ---------------------------------------------------------------------------
// u combine: U[b,n] = K0U / sum_chunks ps. NCH = 16 (from cost) or 64.
// ---------------------------------------------------------------------------
template<int NCH>
__global__ __launch_bounds__(256) void u_combine(
    const float* __restrict__ ps, float* __restrict__ U)
{
    int gid = blockIdx.x * 256 + threadIdx.x;     // over BB*NP
    int b = gid >> 11;
    int n = gid & (NP - 1);
    float S = 0.f;
    #pragma unroll 8
    for (int c = 0; c < NCH; ++c)
        S += ps[((size_t)b * NCH + c) * NP + n];
    U[gid] = K0U / S;
}

// ---------------------------------------------------------------------------
// Final v pass: S_t = sum_n E*U;  P[t,n] = E*U/S as f16. One block per row.
// ---------------------------------------------------------------------------
__global__ __launch_bounds__(256) void v_final(
    const _Float16* __restrict__ E, const float* __restrict__ U,
    _Float16* __restrict__ P)
{
    const int b = blockIdx.y;
    const int t = blockIdx.x;
    const uint4* Eb = (const uint4*)(E + ((size_t)b * TT + t) * NP);
    const float* Ub = U + (size_t)b * NP;
    const int tid = threadIdx.x;

    uint4 w = Eb[tid];
    const int n0 = tid * 8;
    float4 u0 = *(const float4*)(Ub + n0);
    float4 u1 = *(const float4*)(Ub + n0 + 4);
    float ev[8];
    ev[0] = f16u2f((unsigned short)(w.x & 0xFFFFu));
    ev[1] = f16u2f((unsigned short)(w.x >> 16));
    ev[2] = f16u2f((unsigned short)(w.y & 0xFFFFu));
    ev[3] = f16u2f((unsigned short)(w.y >> 16));
    ev[4] = f16u2f((unsigned short)(w.z & 0xFFFFu));
    ev[5] = f16u2f((unsigned short)(w.z >> 16));
    ev[6] = f16u2f((unsigned short)(w.w & 0xFFFFu));
    ev[7] = f16u2f((unsigned short)(w.w >> 16));
    float uv[8] = {u0.x, u0.y, u0.z, u0.w, u1.x, u1.y, u1.z, u1.w};

    float s = 0.f;
    #pragma unroll
    for (int j = 0; j < 8; ++j) s = fmaf(ev[j], uv[j], s);
    #pragma unroll
    for (int off = 32; off; off >>= 1) s += __shfl_down(s, off, 64);

    __shared__ float sw[4];
    __shared__ float Sall;
    if ((tid & 63) == 0) sw[tid >> 6] = s;
    __syncthreads();
    if (tid == 0) Sall = sw[0] + sw[1] + sw[2] + sw[3];
    __syncthreads();
    float invS = 1.0f / Sall;
    _Float16 hp[8];
    #pragma unroll
    for (int j = 0; j < 8; ++j)
        hp[j] = (_Float16)(ev[j] * uv[j] * invS);
    *(f16x8*)(P + ((size_t)b * TT + t) * NP + n0) = *(f16x8*)hp;
}

// ---------------------------------------------------------------------------
// pi GEMM (NT, pure fp16, 3-buffer counted-vmcnt pipeline, 64 K-steps):
//   out[b,t,d] = sum_n P[b,t,n] * vpT[b,d,n]
// 1-D grid, XCD-chunked swizzle (one batch per XCD).
// ---------------------------------------------------------------------------
__global__ __launch_bounds__(256) void gemm_pi_f16(
    const _Float16* __restrict__ P, const _Float16* __restrict__ B,
    float* __restrict__ out)
{
    const int bid = blockIdx.x;
    const int sid = ((bid & 7) << 6) | (bid >> 3);   // 512 blocks, 64/XCD
    const int b  = sid >> 6;
    const int by = (sid >> 2) & 15;
    const int bx = sid & 3;

    const _Float16* Pb = P + (size_t)b * TT * NP;
    const _Float16* Bb = B + (size_t)b * DD * NP;
    float* Cb = out + (size_t)b * TT * DD;

    __shared__ __attribute__((aligned(16))) _Float16 sA[3][4096], sB[3][4096];
    const int tid = threadIdx.x;
    const int lane = tid & 63;
    const int row0 = by * 128;   // t
    const int col0 = bx * 128;   // d
    const int wm = ((tid >> 7) & 1) * 64;
    const int wn = ((tid >> 6) & 1) * 64;
    f32x4 acc[4][4];
    zero_acc(acc);

    auto STAGE = [&](int buf, int k0) {
        #pragma unroll
        for (int q = 0; q < 2; ++q) {
            int o = (tid + (q << 8)) << 4;
            int s = o >> 11;
            int r = (o & 2047) >> 4;
            gload16(Pb + (size_t)(row0 + r) * NP + k0 + s * 8, (char*)&sA[buf][0] + o);
            gload16(Bb + (size_t)(col0 + r) * NP + k0 + s * 8, (char*)&sB[buf][0] + o);
        }
    };

    #define PI_STEP(BUFC, BUFS, KS)                               \
        asm volatile("s_waitcnt vmcnt(4)" ::: "memory");          \
        __builtin_amdgcn_s_barrier();                             \
        __builtin_amdgcn_sched_barrier(0);                        \
        STAGE(BUFS, (KS) * 32);                                   \
        frag_step_f16(&sA[BUFC][0], &sB[BUFC][0], lane, wm, wn, acc);

    STAGE(0, 0);
    STAGE(1, 32);
    for (int s3 = 0; s3 < 60; s3 += 3) {
        PI_STEP(0, 2, s3 + 2)
        PI_STEP(1, 0, s3 + 3)
        PI_STEP(2, 1, s3 + 4)
    }
    PI_STEP(0, 2, 62)      // s = 60
    PI_STEP(1, 0, 63)      // s = 61
    // s = 62: consume buf2 (63-tile still in flight)
    asm volatile("s_waitcnt vmcnt(4)" ::: "memory");
    __builtin_amdgcn_s_barrier();
    __builtin_amdgcn_sched_barrier(0);
    frag_step_f16(&sA[2][0], &sB[2][0], lane, wm, wn, acc);
    // s = 63: drain
    asm volatile("s_waitcnt vmcnt(0)" ::: "memory");
    __builtin_amdgcn_s_barrier();
    __builtin_amdgcn_sched_barrier(0);
    frag_step_f16(&sA[0][0], &sB[0][0], lane, wm, wn, acc);
    #undef PI_STEP

    store_plain(Cb, DD, row0, col0, lane, wm, wn, acc);
}

// ---------------------------------------------------------------------------
extern "C" void kernel_launch(void* const* d_in, const int* in_sizes, int n_in,
                              void* d_out, int out_size, void* d_ws, size_t ws_size,
                              hipStream_t stream)
{
    const float* q  = (const float*)d_in[0];
    const float* k  = (const float*)d_in[1];
    const float* v  = (const float*)d_in[2];
    const float* Qw = (const float*)d_in[3];
    const float* Kw = (const float*)d_in[4];
    const float* Vw = (const float*)d_in[5];
    float* out = (float*)d_out;

    // ---- workspace: ~135 MiB ----
    char* base = (char*)d_ws;
    _Float16* E16 = (_Float16*)base;                                // 64 MiB @ 0
    char* p2 = base + (size_t)BB * TT * NP * 2;
    _Float16* P   = (_Float16*)p2; p2 += (size_t)BB * TT * NP * 2;  // 32 MiB
    _Float16* qpf = (_Float16*)p2; p2 += (size_t)TT * DD * 2;       //  2 MiB
    _Float16* kpf = (_Float16*)p2; p2 += (size_t)BB * NP * DD * 2;  // 16 MiB
    _Float16* vpt = (_Float16*)p2; p2 += (size_t)BB * DD * NP * 2;  // 16 MiB (vpT)
    float* q2 = (float*)p2; p2 += (size_t)TT * 4;
    float* k2 = (float*)p2; p2 += (size_t)BB * NP * 4;
    float* U  = (float*)p2; p2 += (size_t)BB * NP * 4;
    float* ps = (float*)p2; p2 += (size_t)BB * 64 * NP * 4;         // 4 MiB

    // weight f16 temporaries aliased INSIDE E16 (dead before E16 is written):
    _Float16* wq = (_Float16*)base;                 // 3 x 512 KiB
    _Float16* wk = wq + 262144;
    _Float16* wv = wk + 262144;

    dim3 blk(256);

    // Weights: transpose to f16, single launch
    transpose3_f16<<<dim3(8, 8, 3), blk, 0, stream>>>(Qw, Kw, Vw, wq, wk, wv);

    // Projections: q+k merged; v -> vpT direct (both dbuf-prefetched)
    gemm_projqk_f16<<<dim3(4, 144, 1), blk, 0, stream>>>(q, k, wq, wk, qpf);
    gemm_projv_f16<<<dim3(4, 128, 1), blk, 0, stream>>>(v, wv, vpt);

    // Squared norms, merged
    rownorm_f16<<<dim3((TT + BB * NP) / 4), blk, 0, stream>>>(qpf, q2, TT + BB * NP);

    // Cost matrix -> E16 + fused first-u colsum (128x256 tile pipeline)
    gemm_cost_f16<<<dim3(1024), blk, 0, stream>>>(qpf, kpf, q2, k2, E16, ps);

    // Sinkhorn: 5 E-passes total (colsum fused in cost, 4 fused v+u, final v+P)
    u_combine<16><<<dim3(BB * NP / 256), blk, 0, stream>>>(ps, U);
    for (int it = 0; it < 4; ++it) {
        sink_fused<<<dim3(TT / 32, BB), blk, 0, stream>>>(E16, U, ps);
        u_combine<64><<<dim3(BB * NP / 256), blk, 0, stream>>>(ps, U);
    }
    v_final<<<dim3(TT, BB), blk, 0, stream>>>(E16, U, P);

    // out = P @ vp (pure fp16 MFMA, counted-vmcnt pipeline)
    gemm_pi_f16<<<dim3(512), blk, 0, stream>>>(P, vpt, out);
}

// Round 18
// 381.833 us; speedup vs baseline: 1.0134x; 1.0134x over previous
//
#include <hip/hip_runtime.h>
#include <math.h>

#define TT 2048   // tokens
#define NP 2048   // num params (N)
#define BB 8      // batch
#define DD 512    // d_model = kdim = vdim

#define LOG_A (-7.6246189861593985f)  // -log(2048)
#define CC 30.0f                       // E = exp(CC - dist) shift
#define E30 1.0686475e13f              // exp(30)
#define K0U 5.2180055e9f               // exp(30)/2048

typedef __attribute__((ext_vector_type(8))) _Float16 f16x8;
typedef __attribute__((ext_vector_type(4))) _Float16 f16x4;
typedef __attribute__((ext_vector_type(4))) float f32x4;

#define MFMA_F16(a, b, c)  __builtin_amdgcn_mfma_f32_16x16x32_f16((a), (b), (c), 0, 0, 0)

// ---------------------------------------------------------------------------
// helpers
// ---------------------------------------------------------------------------
__device__ __forceinline__ float f16u2f(unsigned short u) {
    union { unsigned short s; _Float16 h; } v; v.s = u;
    return (float)v.h;
}

// async global->LDS, 16B per lane (wave-uniform LDS base + lane*16, per-lane src)
__device__ __forceinline__ void gload16(const void* g, void* l) {
    __builtin_amdgcn_global_load_lds(
        (const __attribute__((address_space(1))) void*)g,
        (__attribute__((address_space(3))) void*)l, 16, 0, 0);
}

// ---------------------------------------------------------------------------
// LDS tile layout, "k-group-major": tile[s][r][8 elems], s = k-subgroup
// (0..3 => BK=32), r = row (0..127). Byte off = s*2048 + r*16.
// A-frag (16x16x32): lane holds A[m=lane%16][k=(lane/16)*8+j]
// B-frag:            lane holds B[k=(lane/16)*8+j][n=lane%16]  (B stored [N][K])
// C/D:               col=lane&15, row=(lane>>4)*4+reg   [m89-verified]
// Frag reads are 256B-contiguous per 16-lane group -> bank-conflict-free
// (SQ_LDS_BANK_CONFLICT == 0 measured R14-R16).
// ---------------------------------------------------------------------------
__device__ __forceinline__ void frag_step_f16(
    const _Float16* sA, const _Float16* sB,
    int lane, int wm, int wn, f32x4 acc[4][4])
{
    const int sb = (lane >> 4) << 11;
    const int rl = (lane & 15) << 4;
    f16x8 a[4], b[4];
    #pragma unroll
    for (int i = 0; i < 4; ++i) {
        a[i] = *(const f16x8*)((const char*)sA + sb + ((wm + i * 16) << 4) + rl);
        b[i] = *(const f16x8*)((const char*)sB + sb + ((wn + i * 16) << 4) + rl);
    }
    __builtin_amdgcn_s_setprio(1);   // T5: favor MFMA-phase wave vs other
    #pragma unroll                   // blocks' stage-issuing waves (m191)
    for (int i = 0; i < 4; ++i)
        #pragma unroll
        for (int j = 0; j < 4; ++j)
            acc[i][j] = MFMA_F16(a[i], b[j], acc[i][j]);
    __builtin_amdgcn_s_setprio(0);
}

__device__ __forceinline__ void zero_acc(f32x4 acc[4][4]) {
    #pragma unroll
    for (int i = 0; i < 4; ++i)
        #pragma unroll
        for (int j = 0; j < 4; ++j)
            acc[i][j] = (f32x4){0.f, 0.f, 0.f, 0.f};
}

__device__ __forceinline__ void store_plain(
    float* C, int N, int row0, int col0, int lane, int wm, int wn, f32x4 acc[4][4])
{
    #pragma unroll
    for (int i = 0; i < 4; ++i)
        #pragma unroll
        for (int j = 0; j < 4; ++j) {
            int colg = col0 + wn + j * 16 + (lane & 15);
            int rowb = row0 + wm + i * 16 + ((lane >> 4) << 2);
            #pragma unroll
            for (int r = 0; r < 4; ++r)
                C[(size_t)(rowb + r) * N + colg] = acc[i][j][r];
        }
}

// ---------------------------------------------------------------------------
// Transpose 3 weights to fp16 in ONE launch. Grid (8,8,3).
// ---------------------------------------------------------------------------
__global__ __launch_bounds__(256) void transpose3_f16(
    const float* __restrict__ X0, const float* __restrict__ X1,
    const float* __restrict__ X2, _Float16* __restrict__ o0,
    _Float16* __restrict__ o1, _Float16* __restrict__ o2)
{
    const int z = blockIdx.z;
    const float* Xb = (z == 0) ? X0 : (z == 1) ? X1 : X2;
    _Float16* ob = (z == 0) ? o0 : (z == 1) ? o1 : o2;
    __shared__ float t[64][65];
    const int bx = blockIdx.x * 64;
    const int by = blockIdx.y * 64;
    const int tx = threadIdx.x & 63, ty = threadIdx.x >> 6;
    #pragma unroll
    for (int r = ty; r < 64; r += 4)
        t[r][tx] = Xb[(size_t)(by + r) * 512 + bx + tx];
    __syncthreads();
    #pragma unroll
    for (int r = ty; r < 64; r += 4)
        ob[(size_t)(bx + r) * 512 + by + tx] = (_Float16)t[tx][r];
}

// ---------------------------------------------------------------------------
// Merged q+k projection GEMM (NT, fp16), 2-phase dbuf prefetch. Grid (4,144).
// ---------------------------------------------------------------------------
__global__ __launch_bounds__(256) void gemm_projqk_f16(
    const float* __restrict__ Aq, const float* __restrict__ Ak,
    const _Float16* __restrict__ Btq, const _Float16* __restrict__ Btk,
    _Float16* __restrict__ C)
{
    const int by = blockIdx.y;
    const bool isq = (by < 16);
    const float* A = isq ? Aq : Ak;
    const _Float16* Bt = isq ? Btq : Btk;
    const int arow0 = isq ? by * 128 : (by - 16) * 128;
    const int crow0 = by * 128;
    const int col0 = blockIdx.x * 128;

    __shared__ __attribute__((aligned(16))) _Float16 sA[2][4096], sB[2][4096];
    const int tid = threadIdx.x;
    const int lane = tid & 63;
    const int wm = ((tid >> 7) & 1) * 64;
    const int wn = ((tid >> 6) & 1) * 64;
    f32x4 acc[4][4];
    zero_acc(acc);

    auto STAGE = [&](int buf, int k0) {
        #pragma unroll
        for (int q = 0; q < 2; ++q) {
            int o = (tid + (q << 8)) << 4;
            int s = o >> 11;
            int r = (o & 2047) >> 4;
            gload16(Bt + (size_t)(col0 + r) * DD + k0 + s * 8, (char*)&sB[buf][0] + o);
            const float* src = A + (size_t)(arow0 + r) * DD + k0 + s * 8;
            float4 f0 = *(const float4*)src;
            float4 f1 = *(const float4*)(src + 4);
            _Float16 hs[8] = {(_Float16)f0.x, (_Float16)f0.y,
                              (_Float16)f0.z, (_Float16)f0.w,
                              (_Float16)f1.x, (_Float16)f1.y,
                              (_Float16)f1.z, (_Float16)f1.w};
            *(f16x8*)((char*)&sA[buf][0] + o) = *(f16x8*)hs;
        }
    };

    STAGE(0, 0);
    __syncthreads();
    int cur = 0;
    for (int k0 = 0; k0 < DD; k0 += 32) {
        if (k0 + 32 < DD) STAGE(cur ^ 1, k0 + 32);
        frag_step_f16(&sA[cur][0], &sB[cur][0], lane, wm, wn, acc);
        __syncthreads();
        cur ^= 1;
    }
    #pragma unroll
    for (int i = 0; i < 4; ++i)
        #pragma unroll
        for (int j = 0; j < 4; ++j) {
            int colg = col0 + wn + j * 16 + (lane & 15);
            int rowb = crow0 + wm + i * 16 + ((lane >> 4) << 2);
            #pragma unroll
            for (int r = 0; r < 4; ++r)
                C[(size_t)(rowb + r) * DD + colg] = (_Float16)acc[i][j][r];
        }
}

// ---------------------------------------------------------------------------
// v projection GEMM (NT, fp16), 2-phase dbuf prefetch: writes vpT directly.
// ---------------------------------------------------------------------------
__global__ __launch_bounds__(256) void gemm_projv_f16(
    const float* __restrict__ A, const _Float16* __restrict__ Bt,
    _Float16* __restrict__ C)
{
    __shared__ __attribute__((aligned(16))) _Float16 sA[2][4096], sB[2][4096];
    const int tid = threadIdx.x;
    const int lane = tid & 63;
    const int row0 = blockIdx.y * 128;
    const int col0 = blockIdx.x * 128;
    const int wm = ((tid >> 7) & 1) * 64;
    const int wn = ((tid >> 6) & 1) * 64;
    f32x4 acc[4][4];
    zero_acc(acc);

    auto STAGE = [&](int buf, int k0) {
        #pragma unroll
        for (int q = 0; q < 2; ++q) {
            int o = (tid + (q << 8)) << 4;
            int s = o >> 11;
            int r = (o & 2047) >> 4;
            gload16(Bt + (size_t)(col0 + r) * DD + k0 + s * 8, (char*)&sB[buf][0] + o);
            const float* src = A + (size_t)(row0 + r) * DD + k0 + s * 8;
            float4 f0 = *(const float4*)src;
            float4 f1 = *(const float4*)(src + 4);
            _Float16 hs[8] = {(_Float16)f0.x, (_Float16)f0.y,
                              (_Float16)f0.z, (_Float16)f0.w,
                              (_Float16)f1.x, (_Float16)f1.y,
                              (_Float16)f1.z, (_Float16)f1.w};
            *(f16x8*)((char*)&sA[buf][0] + o) = *(f16x8*)hs;
        }
    };

    STAGE(0, 0);
    __syncthreads();
    int cur = 0;
    for (int k0 = 0; k0 < DD; k0 += 32) {
        if (k0 + 32 < DD) STAGE(cur ^ 1, k0 + 32);
        frag_step_f16(&sA[cur][0], &sB[cur][0], lane, wm, wn, acc);
        __syncthreads();
        cur ^= 1;
    }
    #pragma unroll
    for (int i = 0; i < 4; ++i)
        #pragma unroll
        for (int j = 0; j < 4; ++j) {
            int colg = col0 + wn + j * 16 + (lane & 15);
            int rowb = row0 + wm + i * 16 + ((lane >> 4) << 2);
            int b = rowb >> 11;
            int n0 = rowb & (NP - 1);
            _Float16 h4[4];
            #pragma unroll
            for (int r = 0; r < 4; ++r) h4[r] = (_Float16)acc[i][j][r];
            *(f16x4*)(C + (size_t)b * DD * NP + (size_t)colg * NP + n0) =
                *(f16x4*)h4;
        }
}

// ---------------------------------------------------------------------------
// Row squared-norm from fp16 (merged qp+kp). One wave per row.
// ---------------------------------------------------------------------------
__global__ __launch_bounds__(256) void rownorm_f16(
    const _Float16* __restrict__ X, float* __restrict__ o, int rows)
{
    int w = blockIdx.x * 4 + (threadIdx.x >> 6);
    int lane = threadIdx.x & 63;
    if (w >= rows) return;
    f16x8 v = *(const f16x8*)(X + (size_t)w * DD + lane * 8);
    float s = 0.f;
    #pragma unroll
    for (int j = 0; j < 8; ++j) {
        float x = (float)v[j];
        s = fmaf(x, x, s);
    }
    #pragma unroll
    for (int off = 32; off; off >>= 1) s += __shfl_down(s, off, 64);
    if (lane == 0) o[w] = s;
}

// ---------------------------------------------------------------------------
// Cost GEMM (NT, fp16, 128x128 tile, 3-buffer counted-vmcnt pipeline —
// R16-proven) + FUSED first-u colsum. Epilogue: dist via v_rsq; scattered
// E stores (R12-proven). Grid 2048, XCD-chunked swizzle (batch per XCD).
// ---------------------------------------------------------------------------
__global__ __launch_bounds__(256) void gemm_cost_f16(
    const _Float16* __restrict__ A, const _Float16* __restrict__ B,
    const float* __restrict__ q2, const float* __restrict__ k2,
    _Float16* __restrict__ E, float* __restrict__ ps16)
{
    const int bid = blockIdx.x;
    const int sid = ((bid & 7) << 8) | (bid >> 3);
    const int b  = sid >> 8;
    const int by = (sid >> 4) & 15;
    const int bx = sid & 15;

    const _Float16* Bb = B + (size_t)b * NP * DD;
    const float* k2b = k2 + (size_t)b * NP;
    _Float16* Cb = E + (size_t)b * TT * NP;

    __shared__ __attribute__((aligned(16))) _Float16 sA[3][4096], sB[3][4096];
    __shared__ float colbuf[2][128];
    const int tid = threadIdx.x;
    const int lane = tid & 63;
    const int row0 = by * 128;   // t
    const int col0 = bx * 128;   // n
    const int wm = ((tid >> 7) & 1) * 64;
    const int wn = ((tid >> 6) & 1) * 64;
    f32x4 acc[4][4];
    zero_acc(acc);

    auto STAGE = [&](int buf, int k0) {
        #pragma unroll
        for (int q = 0; q < 2; ++q) {
            int o = (tid + (q << 8)) << 4;
            int s = o >> 11;
            int r = (o & 2047) >> 4;
            gload16(A + (size_t)(row0 + r) * DD + k0 + s * 8, (char*)&sA[buf][0] + o);
            gload16(Bb + (size_t)(col0 + r) * DD + k0 + s * 8, (char*)&sB[buf][0] + o);
        }
    };

    STAGE(0, 0);
    STAGE(1, 32);
    #pragma unroll
    for (int s = 0; s < 14; ++s) {
        asm volatile("s_waitcnt vmcnt(4)" ::: "memory");
        __builtin_amdgcn_s_barrier();
        __builtin_amdgcn_sched_barrier(0);
        STAGE((s + 2) % 3, (s + 2) * 32);
        frag_step_f16(&sA[s % 3][0], &sB[s % 3][0], lane, wm, wn, acc);
    }
    asm volatile("s_waitcnt vmcnt(4)" ::: "memory");
    __builtin_amdgcn_s_barrier();
    __builtin_amdgcn_sched_barrier(0);
    frag_step_f16(&sA[2][0], &sB[2][0], lane, wm, wn, acc);
    asm volatile("s_waitcnt vmcnt(0)" ::: "memory");
    __builtin_amdgcn_s_barrier();
    __builtin_amdgcn_sched_barrier(0);
    frag_step_f16(&sA[0][0], &sB[0][0], lane, wm, wn, acc);

    // epilogue: E stores (scattered, R12-proven) + per-lane colsum
    float csum[4] = {0.f, 0.f, 0.f, 0.f};
    #pragma unroll
    for (int i = 0; i < 4; ++i)
        #pragma unroll
        for (int j = 0; j < 4; ++j) {
            int colg = col0 + wn + j * 16 + (lane & 15);
            float k2v = k2b[colg];
            int rowb = row0 + wm + i * 16 + ((lane >> 4) << 2);
            #pragma unroll
            for (int r = 0; r < 4; ++r) {
                float sq = fmaxf(q2[rowb + r] + k2v - 2.f * acc[i][j][r], 0.f);
                float dist = sq * __frsqrt_rn(fmaxf(sq, 1e-20f));
                float e = fminf(__expf(CC - dist), 60000.f);
                csum[j] += e;
                Cb[(size_t)(rowb + r) * NP + colg] = (_Float16)e;
            }
        }
    // reduce the 4 lanes (lane>>4 groups) sharing each column
    #pragma unroll
    for (int j = 0; j < 4; ++j) {
        float s = csum[j];
        s += __shfl_down(s, 32, 64);
        s += __shfl_down(s, 16, 64);
        if (lane < 16)
            colbuf[wm >> 6][wn + j * 16 + lane] = s;
    }
    __syncthreads();
    if (tid < 128)
        ps16[((size_t)b * 16 + by) * NP + col0 + tid] =
            colbuf[0][tid] + colbuf[1][tid];
}

// ---------------------------------------------------------------------------
// Fused Sinkhorn pass: block = 32 rows x 2048 cols. Per 8-row group:
// S_t = sum E*U -> Y = E30/S (in-kernel), then colsum E*Y -> ps[b][chunk][n].
// Grid (TT/32, BB) = 512 blocks, 64 chunks.
// ---------------------------------------------------------------------------
__global__ __launch_bounds__(256) void sink_fused(
    const _Float16* __restrict__ E, const float* __restrict__ U,
    float* __restrict__ ps)
{
    const int b = blockIdx.y;
    const int t0 = blockIdx.x * 32;
    const int tid = threadIdx.x;
    const int n0 = tid * 8;
    const _Float16* Eb = E + ((size_t)b * TT + t0) * NP;

    float u8[8];
    {
        float4 a = *(const float4*)(U + (size_t)b * NP + n0);
        float4 c = *(const float4*)(U + (size_t)b * NP + n0 + 4);
        u8[0] = a.x; u8[1] = a.y; u8[2] = a.z; u8[3] = a.w;
        u8[4] = c.x; u8[5] = c.y; u8[6] = c.z; u8[7] = c.w;
    }

    float cs[8] = {0.f, 0.f, 0.f, 0.f, 0.f, 0.f, 0.f, 0.f};
    __shared__ float red[8][256];
    __shared__ float yy[8];

    #pragma unroll
    for (int g = 0; g < 4; ++g) {
        uint4 ev[8];
        #pragma unroll
        for (int r = 0; r < 8; ++r)
            ev[r] = *(const uint4*)(Eb + (size_t)(g * 8 + r) * NP + n0);

        #pragma unroll
        for (int r = 0; r < 8; ++r) {
            float d = 0.f;
            d = fmaf(f16u2f((unsigned short)(ev[r].x & 0xFFFFu)), u8[0], d);
            d = fmaf(f16u2f((unsigned short)(ev[r].x >> 16)),     u8[1], d);
            d = fmaf(f16u2f((unsigned short)(ev[r].y & 0xFFFFu)), u8[2], d);
            d = fmaf(f16u2f((unsigned short)(ev[r].y >> 16)),     u8[3], d);
            d = fmaf(f16u2f((unsigned short)(ev[r].z & 0xFFFFu)), u8[4], d);
            d = fmaf(f16u2f((unsigned short)(ev[r].z >> 16)),     u8[5], d);
            d = fmaf(f16u2f((unsigned short)(ev[r].w & 0xFFFFu)), u8[6], d);
            d = fmaf(f16u2f((unsigned short)(ev[r].w >> 16)),     u8[7], d);
            red[r][tid] = d;
        }
        __syncthreads();
        {
            int w = tid >> 6, lane = tid & 63;
            #pragma unroll
            for (int rr = 0; rr < 2; ++rr) {
                int r = w * 2 + rr;
                float s = red[r][lane] + red[r][lane + 64] +
                          red[r][lane + 128] + red[r][lane + 192];
                #pragma unroll
                for (int off = 32; off; off >>= 1)
                    s += __shfl_down(s, off, 64);
                if (lane == 0) yy[r] = E30 / s;
            }
        }
        __syncthreads();
        #pragma unroll
        for (int r = 0; r < 8; ++r) {
            float yv = yy[r];
            cs[0] = fmaf(f16u2f((unsigned short)(ev[r].x & 0xFFFFu)), yv, cs[0]);
            cs[1] = fmaf(f16u2f((unsigned short)(ev[r].x >> 16)),     yv, cs[1]);
            cs[2] = fmaf(f16u2f((unsigned short)(ev[r].y & 0xFFFFu)), yv, cs[2]);
            cs[3] = fmaf(f16u2f((unsigned short)(ev[r].y >> 16)),     yv, cs[3]);
            cs[4] = fmaf(f16u2f((unsigned short)(ev[r].z & 0xFFFFu)), yv, cs[4]);
            cs[5] = fmaf(f16u2f((unsigned short)(ev[r].z >> 16)),     yv, cs[5]);
            cs[6] = fmaf(f16u2f((unsigned short)(ev[r].w & 0xFFFFu)), yv, cs[6]);
            cs[7] = fmaf(f16u2f((unsigned short)(ev[r].w >> 16)),     yv, cs[7]);
        }
        __syncthreads();
    }

    size_t o = ((size_t)b * 64 + blockIdx.x) * NP + n0;
    *(float4*)(ps + o)     = make_float4(cs[0], cs[1], cs[2], cs[3]);
    *(float4*)(ps + o + 4) = make_float4(cs[4], cs[5], cs[6], cs[7]);
}

// ---------------------------------------------------------------------------
// u combine: U[b,n] = K0U / sum_chunks ps. NCH = 16 (from cost) or 64.
// ---------------------------------------------------------------------------
template<int NCH>
__global__ __launch_bounds__(256) void u_combine(
    const float* __restrict__ ps, float* __restrict__ U)
{
    int gid = blockIdx.x * 256 + threadIdx.x;     // over BB*NP
    int b = gid >> 11;
    int n = gid & (NP - 1);
    float S = 0.f;
    #pragma unroll 8
    for (int c = 0; c < NCH; ++c)
        S += ps[((size_t)b * NCH + c) * NP + n];
    U[gid] = K0U / S;
}

// ---------------------------------------------------------------------------
// Final v pass: S_t = sum_n E*U;  P[t,n] = E*U/S as f16. One block per row.
// ---------------------------------------------------------------------------
__global__ __launch_bounds__(256) void v_final(
    const _Float16* __restrict__ E, const float* __restrict__ U,
    _Float16* __restrict__ P)
{
    const int b = blockIdx.y;
    const int t = blockIdx.x;
    const uint4* Eb = (const uint4*)(E + ((size_t)b * TT + t) * NP);
    const float* Ub = U + (size_t)b * NP;
    const int tid = threadIdx.x;

    uint4 w = Eb[tid];
    const int n0 = tid * 8;
    float4 u0 = *(const float4*)(Ub + n0);
    float4 u1 = *(const float4*)(Ub + n0 + 4);
    float ev[8];
    ev[0] = f16u2f((unsigned short)(w.x & 0xFFFFu));
    ev[1] = f16u2f((unsigned short)(w.x >> 16));
    ev[2] = f16u2f((unsigned short)(w.y & 0xFFFFu));
    ev[3] = f16u2f((unsigned short)(w.y >> 16));
    ev[4] = f16u2f((unsigned short)(w.z & 0xFFFFu));
    ev[5] = f16u2f((unsigned short)(w.z >> 16));
    ev[6] = f16u2f((unsigned short)(w.w & 0xFFFFu));
    ev[7] = f16u2f((unsigned short)(w.w >> 16));
    float uv[8] = {u0.x, u0.y, u0.z, u0.w, u1.x, u1.y, u1.z, u1.w};

    float s = 0.f;
    #pragma unroll
    for (int j = 0; j < 8; ++j) s = fmaf(ev[j], uv[j], s);
    #pragma unroll
    for (int off = 32; off; off >>= 1) s += __shfl_down(s, off, 64);

    __shared__ float sw[4];
    __shared__ float Sall;
    if ((tid & 63) == 0) sw[tid >> 6] = s;
    __syncthreads();
    if (tid == 0) Sall = sw[0] + sw[1] + sw[2] + sw[3];
    __syncthreads();
    float invS = 1.0f / Sall;
    _Float16 hp[8];
    #pragma unroll
    for (int j = 0; j < 8; ++j)
        hp[j] = (_Float16)(ev[j] * uv[j] * invS);
    *(f16x8*)(P + ((size_t)b * TT + t) * NP + n0) = *(f16x8*)hp;
}

// ---------------------------------------------------------------------------
// pi GEMM (NT, pure fp16, 3-buffer counted-vmcnt pipeline, 64 K-steps):
//   out[b,t,d] = sum_n P[b,t,n] * vpT[b,d,n]
// 1-D grid, XCD-chunked swizzle (one batch per XCD).
// ---------------------------------------------------------------------------
__global__ __launch_bounds__(256) void gemm_pi_f16(
    const _Float16* __restrict__ P, const _Float16* __restrict__ B,
    float* __restrict__ out)
{
    const int bid = blockIdx.x;
    const int sid = ((bid & 7) << 6) | (bid >> 3);   // 512 blocks, 64/XCD
    const int b  = sid >> 6;
    const int by = (sid >> 2) & 15;
    const int bx = sid & 3;

    const _Float16* Pb = P + (size_t)b * TT * NP;
    const _Float16* Bb = B + (size_t)b * DD * NP;
    float* Cb = out + (size_t)b * TT * DD;

    __shared__ __attribute__((aligned(16))) _Float16 sA[3][4096], sB[3][4096];
    const int tid = threadIdx.x;
    const int lane = tid & 63;
    const int row0 = by * 128;   // t
    const int col0 = bx * 128;   // d
    const int wm = ((tid >> 7) & 1) * 64;
    const int wn = ((tid >> 6) & 1) * 64;
    f32x4 acc[4][4];
    zero_acc(acc);

    auto STAGE = [&](int buf, int k0) {
        #pragma unroll
        for (int q = 0; q < 2; ++q) {
            int o = (tid + (q << 8)) << 4;
            int s = o >> 11;
            int r = (o & 2047) >> 4;
            gload16(Pb + (size_t)(row0 + r) * NP + k0 + s * 8, (char*)&sA[buf][0] + o);
            gload16(Bb + (size_t)(col0 + r) * NP + k0 + s * 8, (char*)&sB[buf][0] + o);
        }
    };

    #define PI_STEP(BUFC, BUFS, KS)                               \
        asm volatile("s_waitcnt vmcnt(4)" ::: "memory");          \
        __builtin_amdgcn_s_barrier();                             \
        __builtin_amdgcn_sched_barrier(0);                        \
        STAGE(BUFS, (KS) * 32);                                   \
        frag_step_f16(&sA[BUFC][0], &sB[BUFC][0], lane, wm, wn, acc);

    STAGE(0, 0);
    STAGE(1, 32);
    for (int s3 = 0; s3 < 60; s3 += 3) {
        PI_STEP(0, 2, s3 + 2)
        PI_STEP(1, 0, s3 + 3)
        PI_STEP(2, 1, s3 + 4)
    }
    PI_STEP(0, 2, 62)      // s = 60
    PI_STEP(1, 0, 63)      // s = 61
    // s = 62: consume buf2 (63-tile still in flight)
    asm volatile("s_waitcnt vmcnt(4)" ::: "memory");
    __builtin_amdgcn_s_barrier();
    __builtin_amdgcn_sched_barrier(0);
    frag_step_f16(&sA[2][0], &sB[2][0], lane, wm, wn, acc);
    // s = 63: drain
    asm volatile("s_waitcnt vmcnt(0)" ::: "memory");
    __builtin_amdgcn_s_barrier();
    __builtin_amdgcn_sched_barrier(0);
    frag_step_f16(&sA[0][0], &sB[0][0], lane, wm, wn, acc);
    #undef PI_STEP

    store_plain(Cb, DD, row0, col0, lane, wm, wn, acc);
}

// ---------------------------------------------------------------------------
extern "C" void kernel_launch(void* const* d_in, const int* in_sizes, int n_in,
                              void* d_out, int out_size, void* d_ws, size_t ws_size,
                              hipStream_t stream)
{
    const float* q  = (const float*)d_in[0];
    const float* k  = (const float*)d_in[1];
    const float* v  = (const float*)d_in[2];
    const float* Qw = (const float*)d_in[3];
    const float* Kw = (const float*)d_in[4];
    const float* Vw = (const float*)d_in[5];
    float* out = (float*)d_out;

    // ---- workspace: ~135 MiB ----
    char* base = (char*)d_ws;
    _Float16* E16 = (_Float16*)base;                                // 64 MiB @ 0
    char* p2 = base + (size_t)BB * TT * NP * 2;
    _Float16* P   = (_Float16*)p2; p2 += (size_t)BB * TT * NP * 2;  // 32 MiB
    _Float16* qpf = (_Float16*)p2; p2 += (size_t)TT * DD * 2;       //  2 MiB
    _Float16* kpf = (_Float16*)p2; p2 += (size_t)BB * NP * DD * 2;  // 16 MiB
    _Float16* vpt = (_Float16*)p2; p2 += (size_t)BB * DD * NP * 2;  // 16 MiB (vpT)
    float* q2 = (float*)p2; p2 += (size_t)TT * 4;
    float* k2 = (float*)p2; p2 += (size_t)BB * NP * 4;
    float* U  = (float*)p2; p2 += (size_t)BB * NP * 4;
    float* ps = (float*)p2; p2 += (size_t)BB * 64 * NP * 4;         // 4 MiB

    // weight f16 temporaries aliased INSIDE E16 (dead before E16 is written):
    _Float16* wq = (_Float16*)base;                 // 3 x 512 KiB
    _Float16* wk = wq + 262144;
    _Float16* wv = wk + 262144;

    dim3 blk(256);

    // Weights: transpose to f16, single launch
    transpose3_f16<<<dim3(8, 8, 3), blk, 0, stream>>>(Qw, Kw, Vw, wq, wk, wv);

    // Projections: q+k merged; v -> vpT direct (both dbuf-prefetched)
    gemm_projqk_f16<<<dim3(4, 144, 1), blk, 0, stream>>>(q, k, wq, wk, qpf);
    gemm_projv_f16<<<dim3(4, 128, 1), blk, 0, stream>>>(v, wv, vpt);

    // Squared norms, merged
    rownorm_f16<<<dim3((TT + BB * NP) / 4), blk, 0, stream>>>(qpf, q2, TT + BB * NP);

    // Cost matrix -> E16 + fused first-u colsum (R16 128x128 pipeline)
    gemm_cost_f16<<<dim3(2048), blk, 0, stream>>>(qpf, kpf, q2, k2, E16, ps);

    // Sinkhorn: 5 E-passes total (colsum fused in cost, 4 fused v+u, final v+P)
    u_combine<16><<<dim3(BB * NP / 256), blk, 0, stream>>>(ps, U);
    for (int it = 0; it < 4; ++it) {
        sink_fused<<<dim3(TT / 32, BB), blk, 0, stream>>>(E16, U, ps);
        u_combine<64><<<dim3(BB * NP / 256), blk, 0, stream>>>(ps, U);
    }
    v_final<<<dim3(TT, BB), blk, 0, stream>>>(E16, U, P);

    // out = P @ vp (pure fp16 MFMA, counted-vmcnt pipeline)
    gemm_pi_f16<<<dim3(512), blk, 0, stream>>>(P, vpt, out);
}